// Round 13
// baseline (327.580 us; speedup 1.0000x reference)
//
#include <hip/hip_runtime.h>

typedef unsigned short u16;
typedef unsigned int u32;

#define T_SEQ 2048
#define NHEAD 16
#define HDIM 64
#define CDIM 1024
#define W_HSTR (512*2048)
// P: per head 136 causal tiles of 128x128 fp16, row-major tiles
#define P_HSTR 2228224   // 136*16384 elems
#define P_TILE 16384

// Octonion sign table: SG[a][n] = sign of component (a^n) of e_a * e_n.
// Byte a holds row a; bit n set => negative. (Validated end-to-end rounds 3-8.)
#define SGBITS 0xB2D8741EACC66A00ULL

// exp(s*0.125) = exp2(s*0.125/ln2); extra 2^-12 scale keeps unnormalized Z in fp16 range.
#define EXP2C 0.18033688011112042f

typedef _Float16 f16x8 __attribute__((ext_vector_type(8)));
typedef float f32x4 __attribute__((ext_vector_type(4)));

__device__ __forceinline__ float h2f(u16 u) { _Float16 h; __builtin_memcpy(&h, &u, 2); return (float)h; }
__device__ __forceinline__ u16 f2h(float f) { _Float16 h = (_Float16)f; u16 u; __builtin_memcpy(&u, &h, 2); return u; }
__device__ __forceinline__ u32 pk(float a, float b) { return (u32)f2h(a) | ((u32)f2h(b) << 16); }

// async 16B/lane global->LDS DMA; lds dest wave-uniform (HW adds lane*16)
__device__ __forceinline__ void gload16(const u16* g, u16* l) {
    __builtin_amdgcn_global_load_lds((const __attribute__((address_space(1))) u32*)g,
                                     (__attribute__((address_space(3))) u32*)l, 16, 0, 0);
}

// ---- 64x128-tile MFMA core (round-10 proven: grid utilization for skinny GEMMs) ----
// Fragment-major LDS (A seg 0..3, B seg 0..7); 4 waves as 2 wr x 2 wc; acc[2][4].
template<bool F16OUT>
__device__ __forceinline__ void hgemm64_tile(const u16* __restrict__ At, int lda,
                                             const u16* __restrict__ Bt, int ldb, int K,
                                             float* __restrict__ Cf, u16* __restrict__ Ch,
                                             int ldc, u16* As, u16* Bs) {
    int t = threadIdx.x;
    int wave = t >> 6, l = t & 63;
    int wr = wave & 1, wc = wave >> 1;
    int quad = l >> 4, lr = l & 15;
    int acol = quad * 8;
    f32x4 acc[2][4];
#pragma unroll
    for (int i = 0; i < 2; ++i)
#pragma unroll
        for (int j = 0; j < 4; ++j) acc[i][j] = (f32x4){0.f, 0.f, 0.f, 0.f};
    for (int k0 = 0; k0 < K; k0 += 64) {
#pragma unroll
        for (int j = 0; j < 2; ++j) {           // A slots: 8 total (kb 0..1 x seg 0..3)
            int dA = wave * 2 + j;
            int kb = dA >> 2, seg = dA & 3;
            gload16(At + (size_t)(seg * 16 + lr) * lda + k0 + kb * 32 + acol, As + dA * 512);
        }
#pragma unroll
        for (int j = 0; j < 4; ++j) {           // B slots: 16 total (kb 0..1 x seg 0..7)
            int dB = wave * 4 + j;
            int kb = dB >> 3, seg = dB & 7;
            gload16(Bt + (size_t)(seg * 16 + lr) * ldb + k0 + kb * 32 + acol, Bs + dB * 512);
        }
        __syncthreads();
#pragma unroll
        for (int kb = 0; kb < 2; ++kb) {
            f16x8 af[2], bf[4];
#pragma unroll
            for (int mi = 0; mi < 2; ++mi) af[mi] = *(const f16x8*)&As[(kb * 4 + wr * 2 + mi) * 512 + l * 8];
#pragma unroll
            for (int ni = 0; ni < 4; ++ni) bf[ni] = *(const f16x8*)&Bs[(kb * 8 + wc * 4 + ni) * 512 + l * 8];
#pragma unroll
            for (int mi = 0; mi < 2; ++mi)
#pragma unroll
                for (int ni = 0; ni < 4; ++ni)
                    acc[mi][ni] = __builtin_amdgcn_mfma_f32_16x16x32_f16(af[mi], bf[ni], acc[mi][ni], 0, 0, 0);
        }
        __syncthreads();
    }
#pragma unroll
    for (int mi = 0; mi < 2; ++mi)
#pragma unroll
        for (int ni = 0; ni < 4; ++ni)
#pragma unroll
            for (int rr = 0; rr < 4; ++rr) {
                int gr = wr * 32 + mi * 16 + quad * 4 + rr;
                int gc = wc * 64 + ni * 16 + lr;
                float v = acc[mi][ni][rr];
                if (F16OUT) Ch[(size_t)gr * ldc + gc] = f2h(v);
                else Cf[(size_t)gr * ldc + gc] = v;
            }
}

__global__ __launch_bounds__(256) void hgemm_f32(const u16* __restrict__ A, int lda,
                                                 const u16* __restrict__ B, int ldb,
                                                 float* __restrict__ C, int ldc, int K) {
    __shared__ u16 As[4096], Bs[8192];
    int bm = blockIdx.y * 64, bn = blockIdx.x * 128;
    hgemm64_tile<false>(A + (size_t)bm * lda, lda, B + (size_t)bn * ldb, ldb, K,
                        C + (size_t)bm * ldc + bn, nullptr, ldc, As, Bs);
}

__global__ __launch_bounds__(256) void hgemm_f16(const u16* __restrict__ A, int lda,
                                                 const u16* __restrict__ B, int ldb,
                                                 u16* __restrict__ C, int ldc, int K) {
    __shared__ u16 As[4096], Bs[8192];
    int bm = blockIdx.y * 64, bn = blockIdx.x * 128;
    hgemm64_tile<true>(A + (size_t)bm * lda, lda, B + (size_t)bn * ldb, ldb, K,
                       nullptr, C + (size_t)bm * ldc + bn, ldc, As, Bs);
}

// ---- Merged kernel (round 13): qk_exp_p (blocks 0..2175) + w_pre (blocks 2176..2687) ----
// Parts are independent (both depend only on prep_rope outputs); merging saves one
// launch gap and lets w_pre's 512 blocks fill the qk tail. Shared LDS: Pt (36,864B)
// aliased as kcs/vs (33,280B) for the w_pre part.
// qk part ALSO computes l[h][i] = sum_j P (fp32, pre-rounding) via 4-step shfl_xor
// over lr + atomicAdd -> lbuf (zeroed by prep_rope). l is thus ready before pw_gemm,
// which divides in its epilogue (scale_y kernel + ones-MFMA eliminated).
__global__ __launch_bounds__(256) void qk_w(const u16* __restrict__ q16,
                                            const u16* __restrict__ k16,
                                            const float* __restrict__ kc,
                                            const u16* __restrict__ qkv,
                                            u16* __restrict__ P,
                                            u16* __restrict__ W,
                                            float* __restrict__ lbuf) {
    __shared__ u16 smem[128 * 144];
    int t = threadIdx.x;
    if (blockIdx.x < 2176) {
        u16* Pt = smem;
        int idx = blockIdx.x;
        int h = idx & 15;
        int tt = idx >> 4;                   // 0..135 triangular tile index
        int rb = 0;
        while ((rb + 1) * (rb + 2) / 2 <= tt) rb++;
        int cb = tt - rb * (rb + 1) / 2;     // 0..rb
        int wave = t >> 6, l = t & 63;
        int wm = wave & 1, wn = wave >> 1;
        int quad = l >> 4, lr = l & 15;

        const u16* qbase = q16 + (size_t)(rb * 128 + wm * 64 + lr) * CDIM + h * HDIM + quad * 8;
        const u16* kbase = k16 + (size_t)(cb * 128 + wn * 64 + lr) * CDIM + h * HDIM + quad * 8;
        f16x8 qa[4][2], kf[4][2];
#pragma unroll
        for (int mi = 0; mi < 4; ++mi)
#pragma unroll
            for (int kb = 0; kb < 2; ++kb)
                qa[mi][kb] = *(const f16x8*)(qbase + (size_t)(mi * 16) * CDIM + kb * 32);
#pragma unroll
        for (int ni = 0; ni < 4; ++ni)
#pragma unroll
            for (int kb = 0; kb < 2; ++kb)
                kf[ni][kb] = *(const f16x8*)(kbase + (size_t)(ni * 16) * CDIM + kb * 32);

        f32x4 s[4][4];
#pragma unroll
        for (int mi = 0; mi < 4; ++mi)
#pragma unroll
            for (int ni = 0; ni < 4; ++ni) s[mi][ni] = (f32x4){0.f, 0.f, 0.f, 0.f};
#pragma unroll
        for (int kb = 0; kb < 2; ++kb)
#pragma unroll
            for (int mi = 0; mi < 4; ++mi)
#pragma unroll
                for (int ni = 0; ni < 4; ++ni)
                    s[mi][ni] = __builtin_amdgcn_mfma_f32_16x16x32_f16(qa[mi][kb], kf[ni][kb], s[mi][ni], 0, 0, 0);

        float rs[4][4];
#pragma unroll
        for (int mi = 0; mi < 4; ++mi)
#pragma unroll
            for (int rr = 0; rr < 4; ++rr) rs[mi][rr] = 0.f;

#pragma unroll
        for (int mi = 0; mi < 4; ++mi) {
            int row = wm * 64 + mi * 16 + quad * 4;
#pragma unroll
            for (int ni = 0; ni < 4; ++ni) {
                int col = wn * 64 + ni * 16 + lr;
#pragma unroll
                for (int rr = 0; rr < 4; ++rr) {
                    bool valid = (cb < rb) | (col <= row + rr);   // same 128-block => local compare
                    float p = valid ? __builtin_amdgcn_exp2f(s[mi][ni][rr] * EXP2C - 12.f) : 0.f;
                    rs[mi][rr] += p;
                    Pt[(row + rr) * 144 + col] = f2h(p);
                }
            }
        }
        // row-sum -> lbuf (each wave covers cols wn*64..+64; shfl over lr within quad)
#pragma unroll
        for (int mi = 0; mi < 4; ++mi)
#pragma unroll
            for (int rr = 0; rr < 4; ++rr) {
                float v = rs[mi][rr];
                v += __shfl_xor(v, 1);
                v += __shfl_xor(v, 2);
                v += __shfl_xor(v, 4);
                v += __shfl_xor(v, 8);
                if (lr == 0)
                    atomicAdd(lbuf + h * T_SEQ + rb * 128 + wm * 64 + mi * 16 + quad * 4 + rr, v);
            }
        __syncthreads();
        u16* Pg = P + (size_t)h * P_HSTR + (size_t)tt * P_TILE;
#pragma unroll
        for (int i = 0; i < 8; ++i) {
            int c = i * 256 + t;             // 2048 chunks of 8 elems
            int row = c >> 4, cw = c & 15;
            uint4 v = *(const uint4*)&Pt[row * 144 + cw * 8];
            *(uint4*)(Pg + row * 128 + cw * 8) = v;
        }
    } else {
        // ---- w_pre part ----
        float* kcs = (float*)smem;           // [64][65] flat
        float* vs = kcs + 64 * 65;           // [64][65] flat (total 33,280B <= 36,864B)
        int bid = blockIdx.x - 2176;
        int h = bid >> 5;
        int j0 = (bid & 31) * 64;
        int r = t >> 2, cq = (t & 3) * 16;
        const float* kp = kc + (size_t)(j0 + r) * CDIM + h * HDIM + cq;
        const u16* vp = qkv + (size_t)(j0 + r) * 3072 + 2048 + h * HDIM + cq;
#pragma unroll
        for (int u4 = 0; u4 < 4; ++u4) {
            float4 a = *(const float4*)(kp + u4 * 4);
            ushort4 b = *(const ushort4*)(vp + u4 * 4);
            kcs[r * 65 + cq + u4 * 4 + 0] = a.x; kcs[r * 65 + cq + u4 * 4 + 1] = a.y;
            kcs[r * 65 + cq + u4 * 4 + 2] = a.z; kcs[r * 65 + cq + u4 * 4 + 3] = a.w;
            vs[r * 65 + cq + u4 * 4 + 0] = h2f(b.x); vs[r * 65 + cq + u4 * 4 + 1] = h2f(b.y);
            vs[r * 65 + cq + u4 * 4 + 2] = h2f(b.z); vs[r * 65 + cq + u4 * 4 + 3] = h2f(b.w);
        }
        __syncthreads();
        int j = t & 63, g = t >> 6;
        u16* Wp = W + (size_t)h * W_HSTR + j0 + j;
        for (int ae = g * 16; ae < g * 16 + 16; ++ae) {
            int a = ae >> 3, e = ae & 7;
            u32 mask = 0;
#pragma unroll
            for (int qq = 0; qq < 8; ++qq) {
                int p = a ^ e ^ qq;
                u32 bit = (u32)(((SGBITS >> (a * 8 + p)) ^ (SGBITS >> ((e ^ qq) * 8 + qq))) & 1ULL);
                mask |= bit << qq;
            }
#pragma unroll
            for (int m = 0; m < 8; ++m) {
                float w = 0.f;
#pragma unroll
                for (int qq = 0; qq < 8; ++qq) {
                    float t1 = kcs[j * 65 + m * 8 + (a ^ e ^ qq)] * vs[j * 65 + m * 8 + qq];
                    w = ((mask >> qq) & 1) ? (w - t1) : (w + t1);
                }
                Wp[(size_t)(m * 64 + ae) * T_SEQ] = f2h(w);
            }
        }
    }
}

// ---- Kernel B: Z = P @ W with fused, NORMALIZED contract-y epilogue ----
// Round-6 proven body (8-wave paired jobs, 17 K-units/block, 16 waves/CU).
// Epilogue (round-12 validated indices): wave's 128x64 Z-tile = one m-block
// (m = nq*2+wc; a = 2ni+(lr>>3), e = lr&7); y[i][h*64+m*8+e] =
// (sum_a q16 * acc) / l via 4 FMAs + shfl_xor(8) + linv (l from qk_w's atomicAdd).
__global__ __launch_bounds__(512, 4) void pw_gemm(const u16* __restrict__ P,
                                                  const u16* __restrict__ W,
                                                  const u16* __restrict__ q16,
                                                  u16* __restrict__ y16,
                                                  const float* __restrict__ lbuf) {
    __shared__ u16 As[8192], Bs[8192];
    int b = blockIdx.x;
    int jp = b >> 6;                     // 0..7 rb-pair index
    int i6 = b & 63;
    int h = ((i6 & 7) << 1) | ((i6 >> 3) & 1);
    int nq = i6 >> 4;
    const u16* Bt = W + (size_t)h * W_HSTR + (size_t)(nq * 128) * T_SEQ;
    int t = threadIdx.x;
    int wave = t >> 6, l = t & 63;
    int wr = wave >> 1, wc = wave & 1;   // wave tile: rows wr*32, cols wc*64
    int quad = l >> 4, lr = l & 15;
    int acol = quad * 8;
    int mb = nq * 2 + wc;                // this wave's m-block (0..7)
    int o = lr >> 3;                     // a parity held by this lane

#pragma unroll 1
    for (int jobi = 0; jobi < 2; ++jobi) {
        int rb = jobi ? jp : 15 - jp;    // heavy job first
        int K = (rb + 1) * 128;
        const u16* Ph = P + (size_t)h * P_HSTR + (size_t)(rb * (rb + 1) / 2) * P_TILE;
        f32x4 acc[2][4];
#pragma unroll
        for (int mi = 0; mi < 2; ++mi)
#pragma unroll
            for (int ni = 0; ni < 4; ++ni) acc[mi][ni] = (f32x4){0.f, 0.f, 0.f, 0.f};
        for (int k0 = 0; k0 < K; k0 += 64) {
            const u16* At = Ph + (size_t)(k0 >> 7) * P_TILE + (k0 & 64);  // tile base + k-half
#pragma unroll
            for (int j = 0; j < 2; ++j) {
                int d = wave * 2 + j;
                int kb = d >> 3, seg = d & 7;
                size_t roff = (size_t)(seg * 16 + lr);
                gload16(At + roff * 128 + kb * 32 + acol, As + d * 512);
                gload16(Bt + roff * T_SEQ + k0 + kb * 32 + acol, Bs + d * 512);
            }
            __syncthreads();
#pragma unroll
            for (int kb = 0; kb < 2; ++kb) {
                f16x8 af[2], bf[4];
#pragma unroll
                for (int mi = 0; mi < 2; ++mi) af[mi] = *(const f16x8*)&As[(kb * 8 + wr * 2 + mi) * 512 + l * 8];
#pragma unroll
                for (int ni = 0; ni < 4; ++ni) bf[ni] = *(const f16x8*)&Bs[(kb * 8 + wc * 4 + ni) * 512 + l * 8];
#pragma unroll
                for (int mi = 0; mi < 2; ++mi)
#pragma unroll
                    for (int ni = 0; ni < 4; ++ni)
                        acc[mi][ni] = __builtin_amdgcn_mfma_f32_16x16x32_f16(af[mi], bf[ni], acc[mi][ni], 0, 0, 0);
            }
            __syncthreads();
        }
        // fused contract-y epilogue, normalized by l
#pragma unroll
        for (int mi = 0; mi < 2; ++mi)
#pragma unroll
            for (int rr = 0; rr < 4; ++rr) {
                int row = rb * 128 + wr * 32 + mi * 16 + quad * 4 + rr;
                uint4 qv = *(const uint4*)(q16 + (size_t)row * CDIM + h * HDIM + mb * 8);
                const u32* qw = (const u32*)&qv;
                float psum = 0.f;
#pragma unroll
                for (int ni = 0; ni < 4; ++ni) {
                    float qa = h2f((u16)(qw[ni] >> (o * 16)));   // a = 2*ni + o
                    psum = fmaf(qa, acc[mi][ni][rr], psum);
                }
                psum += __shfl_xor(psum, 8);                     // combine a parities
                if (lr < 8) {
                    float linv = 1.f / lbuf[h * T_SEQ + row];
                    y16[(size_t)row * CDIM + h * HDIM + mb * 8 + lr] = f2h(psum * linv);
                }
            }
    }
}

// fp32 -> fp16 conversions: z=0 x(2M), z=1..4 Wq/Wk/Wv/Wo (1M each) into w16
__global__ __launch_bounds__(256) void cvt5(const float* __restrict__ x, const float* __restrict__ wq,
                                            const float* __restrict__ wk, const float* __restrict__ wv,
                                            const float* __restrict__ wo,
                                            u16* __restrict__ x16, u16* __restrict__ w16) {
    int z = blockIdx.y;
    size_t base = ((size_t)blockIdx.x * 256 + threadIdx.x) * 8;
    const float* src;
    u16* dst;
    size_t cnt;
    if (z == 0) { src = x; dst = x16; cnt = 2097152; }
    else if (z == 1) { src = wq; dst = w16; cnt = 1048576; }
    else if (z == 2) { src = wk; dst = w16 + 1048576; cnt = 1048576; }
    else if (z == 3) { src = wv; dst = w16 + 2097152; cnt = 1048576; }
    else { src = wo; dst = w16 + 3145728; cnt = 1048576; }
    if (base >= cnt) return;
    float4 f0 = *(const float4*)(src + base);
    float4 f1 = *(const float4*)(src + base + 4);
    uint4 o;
    o.x = pk(f0.x, f0.y); o.y = pk(f0.z, f0.w); o.z = pk(f1.x, f1.y); o.w = pk(f1.z, f1.w);
    *(uint4*)(dst + base) = o;
}

// One wave per (t,h): rotary+RMS from fp16 qkv (ld 3072); writes q16,k16 (fp16),
// kc (fp32), and zeroes lbuf[h][t] (consumed via atomicAdd in qk_w).
__global__ __launch_bounds__(256) void prep_rope(const u16* __restrict__ qkv,
                                                 u16* __restrict__ q16, u16* __restrict__ k16,
                                                 float* __restrict__ kc, float* __restrict__ lbuf,
                                                 const float* __restrict__ cosb, const float* __restrict__ sinb) {
    int wave = threadIdx.x >> 6, lane = threadIdx.x & 63;
    int idx = blockIdx.x * 4 + wave;
    int t = idx >> 4, h = idx & 15;
    int d = lane & 31;
    float cs = cosb[t * 32 + d];
    float sn = sinb[t * 32 + d];
    size_t b3 = (size_t)t * 3072 + h * HDIM;
    size_t b1 = (size_t)t * CDIM + h * HDIM;
    if (lane == 0) lbuf[h * T_SEQ + t] = 0.f;

    float xq = h2f(qkv[b3 + lane]);
    float oq = __shfl(xq, lane ^ 32);
    float rq = (lane < 32) ? fmaf(xq, cs, oq * sn) : fmaf(xq, cs, -oq * sn);
    float ssq = rq * rq;
#pragma unroll
    for (int m = 1; m < 64; m <<= 1) ssq += __shfl_xor(ssq, m);
    rq *= rsqrtf(ssq * (1.f / 64.f) + 1e-6f);
    q16[b1 + lane] = f2h(rq);

    float xk = h2f(qkv[b3 + 1024 + lane]);
    float ok = __shfl(xk, lane ^ 32);
    float rk = (lane < 32) ? fmaf(xk, cs, ok * sn) : fmaf(xk, cs, -ok * sn);
    float ssk = rk * rk;
#pragma unroll
    for (int m = 1; m < 64; m <<= 1) ssk += __shfl_xor(ssk, m);
    rk *= rsqrtf(ssk * (1.f / 64.f) + 1e-6f);
    k16[b1 + lane] = f2h(rk);

    float s8 = rk * rk;
    s8 += __shfl_xor(s8, 1); s8 += __shfl_xor(s8, 2); s8 += __shfl_xor(s8, 4);
    float sc2 = 1.f / fmaxf(sqrtf(s8), 1e-12f);
    float kcv = rk * sc2;
    if (lane & 7) kcv = -kcv;  // octonion conjugate
    kc[b1 + lane] = kcv;
}

extern "C" void kernel_launch(void* const* d_in, const int* in_sizes, int n_in,
                              void* d_out, int out_size, void* d_ws, size_t ws_size,
                              hipStream_t stream) {
    const float* x = (const float*)d_in[0];
    const float* cosb = (const float*)d_in[1];
    const float* sinb = (const float*)d_in[2];
    const float* Wq = (const float*)d_in[3];
    const float* Wk = (const float*)d_in[4];
    const float* Wv = (const float*)d_in[5];
    const float* Wo = (const float*)d_in[6];
    float* out = (float*)d_out;
    char* base = (char*)d_ws;
    // workspace layout (round-10 proven offsets; Z region unused)
    u16* qkv16 = (u16*)base;                      // 2048x3072 fp16   12,582,912 B
    float* kc = (float*)(base + 12582912);        // 2048x1024 fp32    8,388,608
    u16* x16 = (u16*)(base + 20971520);           //                   4,194,304
    u16* w16 = (u16*)(base + 25165824);           // 4x 1024x1024 fp16 8,388,608
    u16* q16 = (u16*)(base + 33554432);           //                   4,194,304
    u16* k16 = (u16*)(base + 37748736);           //                   4,194,304
    u16* y16 = (u16*)(base + 41943040);           //                   4,194,304
    u16* W = (u16*)(base + 46137344);             //                  33,554,432
    float* lbuf = (float*)(base + 113246208);     // 16x2048 fp32        131,072
    u16* Pbuf = (u16*)(base + 113377280);         // 16x136 tiles fp16 71,303,168 -> end 184,680,448

    cvt5<<<dim3(1024, 5), 256, 0, stream>>>(x, Wq, Wk, Wv, Wo, x16, w16);
    hgemm_f16<<<dim3(24, 32), 256, 0, stream>>>(x16, CDIM, w16, CDIM, qkv16, 3072, CDIM);
    prep_rope<<<T_SEQ * NHEAD / 4, 256, 0, stream>>>(qkv16, q16, k16, kc, lbuf, cosb, sinb);
    qk_w<<<2176 + 512, 256, 0, stream>>>(q16, k16, kc, qkv16, Pbuf, W, lbuf);
    pw_gemm<<<512, 512, 0, stream>>>(Pbuf, W, q16, y16, lbuf);
    hgemm_f32<<<dim3(8, 32), 256, 0, stream>>>(y16, CDIM, w16 + 3145728, CDIM, out, CDIM, CDIM);
}

// Round 14
// 310.056 us; speedup vs baseline: 1.0565x; 1.0565x over previous
//
#include <hip/hip_runtime.h>

typedef unsigned short u16;
typedef unsigned int u32;

#define T_SEQ 2048
#define NHEAD 16
#define HDIM 64
#define CDIM 1024
#define W_HSTR (512*2048)
// P: per head 136 causal tiles of 128x128 fp16, row-major tiles
#define P_HSTR 2228224   // 136*16384 elems
#define P_TILE 16384

// Octonion sign table: SG[a][n] = sign of component (a^n) of e_a * e_n.
// Byte a holds row a; bit n set => negative. (Validated end-to-end rounds 3-8.)
#define SGBITS 0xB2D8741EACC66A00ULL

// exp(s*0.125) = exp2(s*0.125/ln2); extra 2^-12 scale keeps unnormalized Z in fp16 range.
#define EXP2C 0.18033688011112042f

typedef _Float16 f16x8 __attribute__((ext_vector_type(8)));
typedef float f32x4 __attribute__((ext_vector_type(4)));

__device__ __forceinline__ float h2f(u16 u) { _Float16 h; __builtin_memcpy(&h, &u, 2); return (float)h; }
__device__ __forceinline__ u16 f2h(float f) { _Float16 h = (_Float16)f; u16 u; __builtin_memcpy(&u, &h, 2); return u; }
__device__ __forceinline__ u32 pk(float a, float b) { return (u32)f2h(a) | ((u32)f2h(b) << 16); }

// async 16B/lane global->LDS DMA; lds dest wave-uniform (HW adds lane*16)
__device__ __forceinline__ void gload16(const u16* g, u16* l) {
    __builtin_amdgcn_global_load_lds((const __attribute__((address_space(1))) u32*)g,
                                     (__attribute__((address_space(3))) u32*)l, 16, 0, 0);
}

// ---- 64x128-tile MFMA core (round-10 proven: grid utilization for skinny GEMMs) ----
// Fragment-major LDS (A seg 0..3, B seg 0..7); 4 waves as 2 wr x 2 wc; acc[2][4].
template<bool F16OUT>
__device__ __forceinline__ void hgemm64_tile(const u16* __restrict__ At, int lda,
                                             const u16* __restrict__ Bt, int ldb, int K,
                                             float* __restrict__ Cf, u16* __restrict__ Ch,
                                             int ldc, u16* As, u16* Bs) {
    int t = threadIdx.x;
    int wave = t >> 6, l = t & 63;
    int wr = wave & 1, wc = wave >> 1;
    int quad = l >> 4, lr = l & 15;
    int acol = quad * 8;
    f32x4 acc[2][4];
#pragma unroll
    for (int i = 0; i < 2; ++i)
#pragma unroll
        for (int j = 0; j < 4; ++j) acc[i][j] = (f32x4){0.f, 0.f, 0.f, 0.f};
    for (int k0 = 0; k0 < K; k0 += 64) {
#pragma unroll
        for (int j = 0; j < 2; ++j) {           // A slots: 8 total (kb 0..1 x seg 0..3)
            int dA = wave * 2 + j;
            int kb = dA >> 2, seg = dA & 3;
            gload16(At + (size_t)(seg * 16 + lr) * lda + k0 + kb * 32 + acol, As + dA * 512);
        }
#pragma unroll
        for (int j = 0; j < 4; ++j) {           // B slots: 16 total (kb 0..1 x seg 0..7)
            int dB = wave * 4 + j;
            int kb = dB >> 3, seg = dB & 7;
            gload16(Bt + (size_t)(seg * 16 + lr) * ldb + k0 + kb * 32 + acol, Bs + dB * 512);
        }
        __syncthreads();
#pragma unroll
        for (int kb = 0; kb < 2; ++kb) {
            f16x8 af[2], bf[4];
#pragma unroll
            for (int mi = 0; mi < 2; ++mi) af[mi] = *(const f16x8*)&As[(kb * 4 + wr * 2 + mi) * 512 + l * 8];
#pragma unroll
            for (int ni = 0; ni < 4; ++ni) bf[ni] = *(const f16x8*)&Bs[(kb * 8 + wc * 4 + ni) * 512 + l * 8];
#pragma unroll
            for (int mi = 0; mi < 2; ++mi)
#pragma unroll
                for (int ni = 0; ni < 4; ++ni)
                    acc[mi][ni] = __builtin_amdgcn_mfma_f32_16x16x32_f16(af[mi], bf[ni], acc[mi][ni], 0, 0, 0);
        }
        __syncthreads();
    }
#pragma unroll
    for (int mi = 0; mi < 2; ++mi)
#pragma unroll
        for (int ni = 0; ni < 4; ++ni)
#pragma unroll
            for (int rr = 0; rr < 4; ++rr) {
                int gr = wr * 32 + mi * 16 + quad * 4 + rr;
                int gc = wc * 64 + ni * 16 + lr;
                float v = acc[mi][ni][rr];
                if (F16OUT) Ch[(size_t)gr * ldc + gc] = f2h(v);
                else Cf[(size_t)gr * ldc + gc] = v;
            }
}

__global__ __launch_bounds__(256) void hgemm_f32(const u16* __restrict__ A, int lda,
                                                 const u16* __restrict__ B, int ldb,
                                                 float* __restrict__ C, int ldc, int K) {
    __shared__ u16 As[4096], Bs[8192];
    int bm = blockIdx.y * 64, bn = blockIdx.x * 128;
    hgemm64_tile<false>(A + (size_t)bm * lda, lda, B + (size_t)bn * ldb, ldb, K,
                        C + (size_t)bm * ldc + bn, nullptr, ldc, As, Bs);
}

__global__ __launch_bounds__(256) void hgemm_f16(const u16* __restrict__ A, int lda,
                                                 const u16* __restrict__ B, int ldb,
                                                 u16* __restrict__ C, int ldc, int K) {
    __shared__ u16 As[4096], Bs[8192];
    int bm = blockIdx.y * 64, bn = blockIdx.x * 128;
    hgemm64_tile<true>(A + (size_t)bm * lda, lda, B + (size_t)bn * ldb, ldb, K,
                       nullptr, C + (size_t)bm * ldc + bn, ldc, As, Bs);
}

// ---- Kernel A: one-shot P = exp(QK^T) per 128x128 causal tile + l row-sums ----
// 2176 blocks = 16 heads x 136 tiles. QK direct from global (L2-resident), exp -> LDS,
// coalesced uint4 tile store. ALSO accumulates l[h][i] = sum_j P (fp32 pre-rounding)
// via 4-step shfl_xor over lr + atomicAdd -> lbuf (zeroed by prep_rope; correctness
// validated in round 13). Own kernel => own register budget (round-13 lesson: merging
// with w_pre forced VGPR 160 and 10% occupancy).
__global__ __launch_bounds__(256) void qk_exp_p(const u16* __restrict__ q16,
                                                const u16* __restrict__ k16,
                                                u16* __restrict__ P,
                                                float* __restrict__ lbuf) {
    __shared__ u16 Pt[128 * 144];
    int idx = blockIdx.x;
    int h = idx & 15;
    int tt = idx >> 4;                   // 0..135 triangular tile index
    int rb = 0;
    while ((rb + 1) * (rb + 2) / 2 <= tt) rb++;
    int cb = tt - rb * (rb + 1) / 2;     // 0..rb
    int t = threadIdx.x;
    int wave = t >> 6, l = t & 63;
    int wm = wave & 1, wn = wave >> 1;
    int quad = l >> 4, lr = l & 15;

    const u16* qbase = q16 + (size_t)(rb * 128 + wm * 64 + lr) * CDIM + h * HDIM + quad * 8;
    const u16* kbase = k16 + (size_t)(cb * 128 + wn * 64 + lr) * CDIM + h * HDIM + quad * 8;
    f16x8 qa[4][2], kf[4][2];
#pragma unroll
    for (int mi = 0; mi < 4; ++mi)
#pragma unroll
        for (int kb = 0; kb < 2; ++kb)
            qa[mi][kb] = *(const f16x8*)(qbase + (size_t)(mi * 16) * CDIM + kb * 32);
#pragma unroll
    for (int ni = 0; ni < 4; ++ni)
#pragma unroll
        for (int kb = 0; kb < 2; ++kb)
            kf[ni][kb] = *(const f16x8*)(kbase + (size_t)(ni * 16) * CDIM + kb * 32);

    f32x4 s[4][4];
#pragma unroll
    for (int mi = 0; mi < 4; ++mi)
#pragma unroll
        for (int ni = 0; ni < 4; ++ni) s[mi][ni] = (f32x4){0.f, 0.f, 0.f, 0.f};
#pragma unroll
    for (int kb = 0; kb < 2; ++kb)
#pragma unroll
        for (int mi = 0; mi < 4; ++mi)
#pragma unroll
            for (int ni = 0; ni < 4; ++ni)
                s[mi][ni] = __builtin_amdgcn_mfma_f32_16x16x32_f16(qa[mi][kb], kf[ni][kb], s[mi][ni], 0, 0, 0);

    float rs[4][4];
#pragma unroll
    for (int mi = 0; mi < 4; ++mi)
#pragma unroll
        for (int rr = 0; rr < 4; ++rr) rs[mi][rr] = 0.f;

#pragma unroll
    for (int mi = 0; mi < 4; ++mi) {
        int row = wm * 64 + mi * 16 + quad * 4;
#pragma unroll
        for (int ni = 0; ni < 4; ++ni) {
            int col = wn * 64 + ni * 16 + lr;
#pragma unroll
            for (int rr = 0; rr < 4; ++rr) {
                bool valid = (cb < rb) | (col <= row + rr);   // same 128-block => local compare
                float p = valid ? __builtin_amdgcn_exp2f(s[mi][ni][rr] * EXP2C - 12.f) : 0.f;
                rs[mi][rr] += p;
                Pt[(row + rr) * 144 + col] = f2h(p);
            }
        }
    }
    // row-sum -> lbuf (wave covers cols wn*64..+64; reduce over lr)
#pragma unroll
    for (int mi = 0; mi < 4; ++mi)
#pragma unroll
        for (int rr = 0; rr < 4; ++rr) {
            float v = rs[mi][rr];
            v += __shfl_xor(v, 1);
            v += __shfl_xor(v, 2);
            v += __shfl_xor(v, 4);
            v += __shfl_xor(v, 8);
            if (lr == 0)
                atomicAdd(lbuf + h * T_SEQ + rb * 128 + wm * 64 + mi * 16 + quad * 4 + rr, v);
        }
    __syncthreads();
    u16* Pg = P + (size_t)h * P_HSTR + (size_t)tt * P_TILE;
#pragma unroll
    for (int i = 0; i < 8; ++i) {
        int c = i * 256 + t;             // 2048 chunks of 8 elems
        int row = c >> 4, cw = c & 15;
        uint4 v = *(const uint4*)&Pt[row * 144 + cw * 8];
        *(uint4*)(Pg + row * 128 + cw * 8) = v;
    }
}

// ---- Kernel B: Z = P @ W with fused, NORMALIZED contract-y epilogue ----
// Round-6 proven body (8-wave paired jobs, 17 K-units/block, 16 waves/CU); no
// accl/ones path (l comes from qk_exp_p). Epilogue indices validated rounds 12-13:
// wave's 128x64 Z-tile = one m-block (m = nq*2+wc; a = 2ni+(lr>>3), e = lr&7);
// y[i][h*64+m*8+e] = (sum_a q16*acc)/l via 4 FMAs + shfl_xor(8) + linv.
__global__ __launch_bounds__(512, 4) void pw_gemm(const u16* __restrict__ P,
                                                  const u16* __restrict__ W,
                                                  const u16* __restrict__ q16,
                                                  u16* __restrict__ y16,
                                                  const float* __restrict__ lbuf) {
    __shared__ u16 As[8192], Bs[8192];
    int b = blockIdx.x;
    int jp = b >> 6;                     // 0..7 rb-pair index
    int i6 = b & 63;
    int h = ((i6 & 7) << 1) | ((i6 >> 3) & 1);
    int nq = i6 >> 4;
    const u16* Bt = W + (size_t)h * W_HSTR + (size_t)(nq * 128) * T_SEQ;
    int t = threadIdx.x;
    int wave = t >> 6, l = t & 63;
    int wr = wave >> 1, wc = wave & 1;   // wave tile: rows wr*32, cols wc*64
    int quad = l >> 4, lr = l & 15;
    int acol = quad * 8;
    int mb = nq * 2 + wc;                // this wave's m-block (0..7)
    int o = lr >> 3;                     // a parity held by this lane

#pragma unroll 1
    for (int jobi = 0; jobi < 2; ++jobi) {
        int rb = jobi ? jp : 15 - jp;    // heavy job first
        int K = (rb + 1) * 128;
        const u16* Ph = P + (size_t)h * P_HSTR + (size_t)(rb * (rb + 1) / 2) * P_TILE;
        f32x4 acc[2][4];
#pragma unroll
        for (int mi = 0; mi < 2; ++mi)
#pragma unroll
            for (int ni = 0; ni < 4; ++ni) acc[mi][ni] = (f32x4){0.f, 0.f, 0.f, 0.f};
        for (int k0 = 0; k0 < K; k0 += 64) {
            const u16* At = Ph + (size_t)(k0 >> 7) * P_TILE + (k0 & 64);  // tile base + k-half
#pragma unroll
            for (int j = 0; j < 2; ++j) {
                int d = wave * 2 + j;
                int kb = d >> 3, seg = d & 7;
                size_t roff = (size_t)(seg * 16 + lr);
                gload16(At + roff * 128 + kb * 32 + acol, As + d * 512);
                gload16(Bt + roff * T_SEQ + k0 + kb * 32 + acol, Bs + d * 512);
            }
            __syncthreads();
#pragma unroll
            for (int kb = 0; kb < 2; ++kb) {
                f16x8 af[2], bf[4];
#pragma unroll
                for (int mi = 0; mi < 2; ++mi) af[mi] = *(const f16x8*)&As[(kb * 8 + wr * 2 + mi) * 512 + l * 8];
#pragma unroll
                for (int ni = 0; ni < 4; ++ni) bf[ni] = *(const f16x8*)&Bs[(kb * 8 + wc * 4 + ni) * 512 + l * 8];
#pragma unroll
                for (int mi = 0; mi < 2; ++mi)
#pragma unroll
                    for (int ni = 0; ni < 4; ++ni)
                        acc[mi][ni] = __builtin_amdgcn_mfma_f32_16x16x32_f16(af[mi], bf[ni], acc[mi][ni], 0, 0, 0);
            }
            __syncthreads();
        }
        // fused contract-y epilogue, normalized by l
#pragma unroll
        for (int mi = 0; mi < 2; ++mi)
#pragma unroll
            for (int rr = 0; rr < 4; ++rr) {
                int row = rb * 128 + wr * 32 + mi * 16 + quad * 4 + rr;
                uint4 qv = *(const uint4*)(q16 + (size_t)row * CDIM + h * HDIM + mb * 8);
                const u32* qw = (const u32*)&qv;
                float psum = 0.f;
#pragma unroll
                for (int ni = 0; ni < 4; ++ni) {
                    float qa = h2f((u16)(qw[ni] >> (o * 16)));   // a = 2*ni + o
                    psum = fmaf(qa, acc[mi][ni][rr], psum);
                }
                psum += __shfl_xor(psum, 8);                     // combine a parities
                if (lr < 8) {
                    float linv = 1.f / lbuf[h * T_SEQ + row];
                    y16[(size_t)row * CDIM + h * HDIM + mb * 8 + lr] = f2h(psum * linv);
                }
            }
    }
}

// fp32 -> fp16 conversions: z=0 x(2M), z=1..4 Wq/Wk/Wv/Wo (1M each) into w16
__global__ __launch_bounds__(256) void cvt5(const float* __restrict__ x, const float* __restrict__ wq,
                                            const float* __restrict__ wk, const float* __restrict__ wv,
                                            const float* __restrict__ wo,
                                            u16* __restrict__ x16, u16* __restrict__ w16) {
    int z = blockIdx.y;
    size_t base = ((size_t)blockIdx.x * 256 + threadIdx.x) * 8;
    const float* src;
    u16* dst;
    size_t cnt;
    if (z == 0) { src = x; dst = x16; cnt = 2097152; }
    else if (z == 1) { src = wq; dst = w16; cnt = 1048576; }
    else if (z == 2) { src = wk; dst = w16 + 1048576; cnt = 1048576; }
    else if (z == 3) { src = wv; dst = w16 + 2097152; cnt = 1048576; }
    else { src = wo; dst = w16 + 3145728; cnt = 1048576; }
    if (base >= cnt) return;
    float4 f0 = *(const float4*)(src + base);
    float4 f1 = *(const float4*)(src + base + 4);
    uint4 o;
    o.x = pk(f0.x, f0.y); o.y = pk(f0.z, f0.w); o.z = pk(f1.x, f1.y); o.w = pk(f1.z, f1.w);
    *(uint4*)(dst + base) = o;
}

// One wave per (t,h): rotary+RMS from fp16 qkv (ld 3072); writes q16,k16 (fp16),
// kc (fp32), and zeroes lbuf[h][t] (consumed via atomicAdd in qk_exp_p).
__global__ __launch_bounds__(256) void prep_rope(const u16* __restrict__ qkv,
                                                 u16* __restrict__ q16, u16* __restrict__ k16,
                                                 float* __restrict__ kc, float* __restrict__ lbuf,
                                                 const float* __restrict__ cosb, const float* __restrict__ sinb) {
    int wave = threadIdx.x >> 6, lane = threadIdx.x & 63;
    int idx = blockIdx.x * 4 + wave;
    int t = idx >> 4, h = idx & 15;
    int d = lane & 31;
    float cs = cosb[t * 32 + d];
    float sn = sinb[t * 32 + d];
    size_t b3 = (size_t)t * 3072 + h * HDIM;
    size_t b1 = (size_t)t * CDIM + h * HDIM;
    if (lane == 0) lbuf[h * T_SEQ + t] = 0.f;

    float xq = h2f(qkv[b3 + lane]);
    float oq = __shfl(xq, lane ^ 32);
    float rq = (lane < 32) ? fmaf(xq, cs, oq * sn) : fmaf(xq, cs, -oq * sn);
    float ssq = rq * rq;
#pragma unroll
    for (int m = 1; m < 64; m <<= 1) ssq += __shfl_xor(ssq, m);
    rq *= rsqrtf(ssq * (1.f / 64.f) + 1e-6f);
    q16[b1 + lane] = f2h(rq);

    float xk = h2f(qkv[b3 + 1024 + lane]);
    float ok = __shfl(xk, lane ^ 32);
    float rk = (lane < 32) ? fmaf(xk, cs, ok * sn) : fmaf(xk, cs, -ok * sn);
    float ssk = rk * rk;
#pragma unroll
    for (int m = 1; m < 64; m <<= 1) ssk += __shfl_xor(ssk, m);
    rk *= rsqrtf(ssk * (1.f / 64.f) + 1e-6f);
    k16[b1 + lane] = f2h(rk);

    float s8 = rk * rk;
    s8 += __shfl_xor(s8, 1); s8 += __shfl_xor(s8, 2); s8 += __shfl_xor(s8, 4);
    float sc2 = 1.f / fmaxf(sqrtf(s8), 1e-12f);
    float kcv = rk * sc2;
    if (lane & 7) kcv = -kcv;  // octonion conjugate
    kc[b1 + lane] = kcv;
}

// W[h][n=(m*64+a*8+e)][j] from kc (fp32, ld 1024) and v inside fp16 qkv (ld 3072, +2048)
__global__ __launch_bounds__(256) void w_pre(const float* __restrict__ kc, const u16* __restrict__ qkv,
                                             u16* __restrict__ W) {
    __shared__ float kcs[64][65];
    __shared__ float vs[64][65];
    int h = blockIdx.y;
    int j0 = blockIdx.x * 64;
    int t = threadIdx.x;
    int r = t >> 2, cq = (t & 3) * 16;
    const float* kp = kc + (size_t)(j0 + r) * CDIM + h * HDIM + cq;
    const u16* vp = qkv + (size_t)(j0 + r) * 3072 + 2048 + h * HDIM + cq;
#pragma unroll
    for (int u4 = 0; u4 < 4; ++u4) {
        float4 a = *(const float4*)(kp + u4 * 4);
        ushort4 b = *(const ushort4*)(vp + u4 * 4);
        kcs[r][cq + u4 * 4 + 0] = a.x; kcs[r][cq + u4 * 4 + 1] = a.y;
        kcs[r][cq + u4 * 4 + 2] = a.z; kcs[r][cq + u4 * 4 + 3] = a.w;
        vs[r][cq + u4 * 4 + 0] = h2f(b.x); vs[r][cq + u4 * 4 + 1] = h2f(b.y);
        vs[r][cq + u4 * 4 + 2] = h2f(b.z); vs[r][cq + u4 * 4 + 3] = h2f(b.w);
    }
    __syncthreads();
    int j = t & 63, g = t >> 6;
    u16* Wp = W + (size_t)h * W_HSTR + j0 + j;
    for (int ae = g * 16; ae < g * 16 + 16; ++ae) {
        int a = ae >> 3, e = ae & 7;
        u32 mask = 0;
#pragma unroll
        for (int qq = 0; qq < 8; ++qq) {
            int p = a ^ e ^ qq;
            u32 bit = (u32)(((SGBITS >> (a * 8 + p)) ^ (SGBITS >> ((e ^ qq) * 8 + qq))) & 1ULL);
            mask |= bit << qq;
        }
#pragma unroll
        for (int m = 0; m < 8; ++m) {
            float w = 0.f;
#pragma unroll
            for (int qq = 0; qq < 8; ++qq) {
                float t1 = kcs[j][m * 8 + (a ^ e ^ qq)] * vs[j][m * 8 + qq];
                w = ((mask >> qq) & 1) ? (w - t1) : (w + t1);
            }
            Wp[(size_t)(m * 64 + ae) * T_SEQ] = f2h(w);
        }
    }
}

extern "C" void kernel_launch(void* const* d_in, const int* in_sizes, int n_in,
                              void* d_out, int out_size, void* d_ws, size_t ws_size,
                              hipStream_t stream) {
    const float* x = (const float*)d_in[0];
    const float* cosb = (const float*)d_in[1];
    const float* sinb = (const float*)d_in[2];
    const float* Wq = (const float*)d_in[3];
    const float* Wk = (const float*)d_in[4];
    const float* Wv = (const float*)d_in[5];
    const float* Wo = (const float*)d_in[6];
    float* out = (float*)d_out;
    char* base = (char*)d_ws;
    // workspace layout (round-10 proven offsets; Z region unused)
    u16* qkv16 = (u16*)base;                      // 2048x3072 fp16   12,582,912 B
    float* kc = (float*)(base + 12582912);        // 2048x1024 fp32    8,388,608
    u16* x16 = (u16*)(base + 20971520);           //                   4,194,304
    u16* w16 = (u16*)(base + 25165824);           // 4x 1024x1024 fp16 8,388,608
    u16* q16 = (u16*)(base + 33554432);           //                   4,194,304
    u16* k16 = (u16*)(base + 37748736);           //                   4,194,304
    u16* y16 = (u16*)(base + 41943040);           //                   4,194,304
    u16* W = (u16*)(base + 46137344);             //                  33,554,432
    float* lbuf = (float*)(base + 113246208);     // 16x2048 fp32        131,072
    u16* Pbuf = (u16*)(base + 113377280);         // 16x136 tiles fp16 71,303,168 -> end 184,680,448

    cvt5<<<dim3(1024, 5), 256, 0, stream>>>(x, Wq, Wk, Wv, Wo, x16, w16);
    hgemm_f16<<<dim3(24, 32), 256, 0, stream>>>(x16, CDIM, w16, CDIM, qkv16, 3072, CDIM);
    prep_rope<<<T_SEQ * NHEAD / 4, 256, 0, stream>>>(qkv16, q16, k16, kc, lbuf, cosb, sinb);
    qk_exp_p<<<16 * 136, 256, 0, stream>>>(q16, k16, Pbuf, lbuf);
    w_pre<<<dim3(32, 16), 256, 0, stream>>>(kc, qkv16, W);
    pw_gemm<<<512, 512, 0, stream>>>(Pbuf, W, q16, y16, lbuf);
    hgemm_f32<<<dim3(8, 32), 256, 0, stream>>>(y16, CDIM, w16 + 3145728, CDIM, out, CDIM, CDIM);
}

// Round 15
// 281.748 us; speedup vs baseline: 1.1627x; 1.1005x over previous
//
#include <hip/hip_runtime.h>

typedef unsigned short u16;
typedef unsigned int u32;

#define T_SEQ 2048
#define NHEAD 16
#define HDIM 64
#define CDIM 1024
#define W_HSTR (512*2048)
// P: per head 136 causal tiles of 128x128 fp16, row-major tiles
#define P_HSTR 2228224   // 136*16384 elems
#define P_TILE 16384

// Octonion sign table: SG[a][n] = sign of component (a^n) of e_a * e_n.
// Byte a holds row a; bit n set => negative. (Validated end-to-end rounds 3-8.)
#define SGBITS 0xB2D8741EACC66A00ULL

// exp(s*0.125) = exp2(s*0.125/ln2); extra 2^-12 scale keeps unnormalized Z in fp16 range.
#define EXP2C 0.18033688011112042f

typedef _Float16 f16x8 __attribute__((ext_vector_type(8)));
typedef float f32x4 __attribute__((ext_vector_type(4)));

__device__ __forceinline__ float h2f(u16 u) { _Float16 h; __builtin_memcpy(&h, &u, 2); return (float)h; }
__device__ __forceinline__ u16 f2h(float f) { _Float16 h = (_Float16)f; u16 u; __builtin_memcpy(&u, &h, 2); return u; }
__device__ __forceinline__ u32 pk(float a, float b) { return (u32)f2h(a) | ((u32)f2h(b) << 16); }

// async 16B/lane global->LDS DMA; lds dest wave-uniform (HW adds lane*16)
__device__ __forceinline__ void gload16(const u16* g, u16* l) {
    __builtin_amdgcn_global_load_lds((const __attribute__((address_space(1))) u32*)g,
                                     (__attribute__((address_space(3))) u32*)l, 16, 0, 0);
}

// ---- 64x128-tile MFMA core (round-10 proven: grid utilization for skinny GEMMs) ----
// Fragment-major LDS (A seg 0..3, B seg 0..7); 4 waves as 2 wr x 2 wc; acc[2][4].
template<bool F16OUT>
__device__ __forceinline__ void hgemm64_tile(const u16* __restrict__ At, int lda,
                                             const u16* __restrict__ Bt, int ldb, int K,
                                             float* __restrict__ Cf, u16* __restrict__ Ch,
                                             int ldc, u16* As, u16* Bs) {
    int t = threadIdx.x;
    int wave = t >> 6, l = t & 63;
    int wr = wave & 1, wc = wave >> 1;
    int quad = l >> 4, lr = l & 15;
    int acol = quad * 8;
    f32x4 acc[2][4];
#pragma unroll
    for (int i = 0; i < 2; ++i)
#pragma unroll
        for (int j = 0; j < 4; ++j) acc[i][j] = (f32x4){0.f, 0.f, 0.f, 0.f};
    for (int k0 = 0; k0 < K; k0 += 64) {
#pragma unroll
        for (int j = 0; j < 2; ++j) {           // A slots: 8 total (kb 0..1 x seg 0..3)
            int dA = wave * 2 + j;
            int kb = dA >> 2, seg = dA & 3;
            gload16(At + (size_t)(seg * 16 + lr) * lda + k0 + kb * 32 + acol, As + dA * 512);
        }
#pragma unroll
        for (int j = 0; j < 4; ++j) {           // B slots: 16 total (kb 0..1 x seg 0..7)
            int dB = wave * 4 + j;
            int kb = dB >> 3, seg = dB & 7;
            gload16(Bt + (size_t)(seg * 16 + lr) * ldb + k0 + kb * 32 + acol, Bs + dB * 512);
        }
        __syncthreads();
#pragma unroll
        for (int kb = 0; kb < 2; ++kb) {
            f16x8 af[2], bf[4];
#pragma unroll
            for (int mi = 0; mi < 2; ++mi) af[mi] = *(const f16x8*)&As[(kb * 4 + wr * 2 + mi) * 512 + l * 8];
#pragma unroll
            for (int ni = 0; ni < 4; ++ni) bf[ni] = *(const f16x8*)&Bs[(kb * 8 + wc * 4 + ni) * 512 + l * 8];
#pragma unroll
            for (int mi = 0; mi < 2; ++mi)
#pragma unroll
                for (int ni = 0; ni < 4; ++ni)
                    acc[mi][ni] = __builtin_amdgcn_mfma_f32_16x16x32_f16(af[mi], bf[ni], acc[mi][ni], 0, 0, 0);
        }
        __syncthreads();
    }
#pragma unroll
    for (int mi = 0; mi < 2; ++mi)
#pragma unroll
        for (int ni = 0; ni < 4; ++ni)
#pragma unroll
            for (int rr = 0; rr < 4; ++rr) {
                int gr = wr * 32 + mi * 16 + quad * 4 + rr;
                int gc = wc * 64 + ni * 16 + lr;
                float v = acc[mi][ni][rr];
                if (F16OUT) Ch[(size_t)gr * ldc + gc] = f2h(v);
                else Cf[(size_t)gr * ldc + gc] = v;
            }
}

__global__ __launch_bounds__(256) void hgemm_f32(const u16* __restrict__ A, int lda,
                                                 const u16* __restrict__ B, int ldb,
                                                 float* __restrict__ C, int ldc, int K) {
    __shared__ u16 As[4096], Bs[8192];
    int bm = blockIdx.y * 64, bn = blockIdx.x * 128;
    hgemm64_tile<false>(A + (size_t)bm * lda, lda, B + (size_t)bn * ldb, ldb, K,
                        C + (size_t)bm * ldc + bn, nullptr, ldc, As, Bs);
}

__global__ __launch_bounds__(256) void hgemm_f16(const u16* __restrict__ A, int lda,
                                                 const u16* __restrict__ B, int ldb,
                                                 u16* __restrict__ C, int ldc, int K) {
    __shared__ u16 As[4096], Bs[8192];
    int bm = blockIdx.y * 64, bn = blockIdx.x * 128;
    hgemm64_tile<true>(A + (size_t)bm * lda, lda, B + (size_t)bn * ldb, ldb, K,
                       nullptr, C + (size_t)bm * ldc + bn, ldc, As, Bs);
}

// ---- Kernel A: one-shot P = exp(QK^T) per 128x128 causal tile ----
// 2176 blocks = 16 heads x 136 tiles (rb>=cb). QK direct from global (L2-resident),
// exp -> LDS, then coalesced row-major uint4 tile store. Pad 144 keeps 16B alignment.
__global__ __launch_bounds__(256) void qk_exp_p(const u16* __restrict__ q16,
                                                const u16* __restrict__ k16,
                                                u16* __restrict__ P) {
    __shared__ u16 Pt[128 * 144];
    int idx = blockIdx.x;
    int h = idx & 15;
    int tt = idx >> 4;                   // 0..135 triangular tile index
    int rb = 0;
    while ((rb + 1) * (rb + 2) / 2 <= tt) rb++;
    int cb = tt - rb * (rb + 1) / 2;     // 0..rb
    int t = threadIdx.x;
    int wave = t >> 6, l = t & 63;
    int wm = wave & 1, wn = wave >> 1;
    int quad = l >> 4, lr = l & 15;

    const u16* qbase = q16 + (size_t)(rb * 128 + wm * 64 + lr) * CDIM + h * HDIM + quad * 8;
    const u16* kbase = k16 + (size_t)(cb * 128 + wn * 64 + lr) * CDIM + h * HDIM + quad * 8;
    f16x8 qa[4][2], kf[4][2];
#pragma unroll
    for (int mi = 0; mi < 4; ++mi)
#pragma unroll
        for (int kb = 0; kb < 2; ++kb)
            qa[mi][kb] = *(const f16x8*)(qbase + (size_t)(mi * 16) * CDIM + kb * 32);
#pragma unroll
    for (int ni = 0; ni < 4; ++ni)
#pragma unroll
        for (int kb = 0; kb < 2; ++kb)
            kf[ni][kb] = *(const f16x8*)(kbase + (size_t)(ni * 16) * CDIM + kb * 32);

    f32x4 s[4][4];
#pragma unroll
    for (int mi = 0; mi < 4; ++mi)
#pragma unroll
        for (int ni = 0; ni < 4; ++ni) s[mi][ni] = (f32x4){0.f, 0.f, 0.f, 0.f};
#pragma unroll
    for (int kb = 0; kb < 2; ++kb)
#pragma unroll
        for (int mi = 0; mi < 4; ++mi)
#pragma unroll
            for (int ni = 0; ni < 4; ++ni)
                s[mi][ni] = __builtin_amdgcn_mfma_f32_16x16x32_f16(qa[mi][kb], kf[ni][kb], s[mi][ni], 0, 0, 0);

#pragma unroll
    for (int mi = 0; mi < 4; ++mi) {
        int row = wm * 64 + mi * 16 + quad * 4;
#pragma unroll
        for (int ni = 0; ni < 4; ++ni) {
            int col = wn * 64 + ni * 16 + lr;
#pragma unroll
            for (int rr = 0; rr < 4; ++rr) {
                bool valid = (cb < rb) | (col <= row + rr);   // same 128-block => local compare
                float p = valid ? __builtin_amdgcn_exp2f(s[mi][ni][rr] * EXP2C - 12.f) : 0.f;
                Pt[(row + rr) * 144 + col] = f2h(p);
            }
        }
    }
    __syncthreads();
    u16* Pg = P + (size_t)h * P_HSTR + (size_t)tt * P_TILE;
#pragma unroll
    for (int i = 0; i < 8; ++i) {
        int c = i * 256 + t;             // 2048 chunks of 8 elems
        int row = c >> 4, cw = c & 15;
        uint4 v = *(const uint4*)&Pt[row * 144 + cw * 8];
        *(uint4*)(Pg + row * 128 + cw * 8) = v;
    }
}

// ---- Kernel B: Z = P @ W with fused contract-y epilogue, BK=128 (round 15) ----
// Round-12 proven body (best measured config, 279.15us) with ONE change: K-step
// doubled 64->128. LDS 32->64KB; residency stays 2 blocks/CU (grid=2/CU; 2x64KB
// <= 160KB), so -- unlike m132's regression -- no occupancy is traded. Barriers
// per block: 34 -> 17; the ~1.6k-cycle per-step drain+barrier overhead (R7/8/9:
// un-pipelineable within this structure) is amortized over 2x work.
// Staging: 32 slots/buffer, d = kb*8+seg (kb 0..3 col-chunks, seg 0..7 row-groups);
// k0 is now tile-aligned so the (k0&64) term drops. Fragment formulas unchanged.
// Epilogue (round-12 validated): wave's 128x64 Z-tile = one m-block (m = nq*2+wc;
// a = 2ni+(lr>>3), e = lr&7); y_un = sum_a q16*acc via 4 FMAs + shfl_xor(8).
// l = P.1 via ones-MFMA on nq==0, wc==0 waves; 1/l in scale_y.
__global__ __launch_bounds__(512, 4) void pw_gemm(const u16* __restrict__ P,
                                                  const u16* __restrict__ W,
                                                  const u16* __restrict__ q16,
                                                  u16* __restrict__ y16,
                                                  float* __restrict__ lbuf) {
    __shared__ u16 As[16384], Bs[16384];
    int b = blockIdx.x;
    int jp = b >> 6;                     // 0..7 rb-pair index
    int i6 = b & 63;
    int h = ((i6 & 7) << 1) | ((i6 >> 3) & 1);
    int nq = i6 >> 4;
    const u16* Bt = W + (size_t)h * W_HSTR + (size_t)(nq * 128) * T_SEQ;
    int t = threadIdx.x;
    int wave = t >> 6, l = t & 63;
    int wr = wave >> 1, wc = wave & 1;   // wave tile: rows wr*32, cols wc*64
    int quad = l >> 4, lr = l & 15;
    int acol = quad * 8;
    int mb = nq * 2 + wc;                // this wave's m-block (0..7)
    int o = lr >> 3;                     // a parity held by this lane
    f16x8 ones;
#pragma unroll
    for (int j = 0; j < 8; ++j) ones[j] = (_Float16)1.0f;

#pragma unroll 1
    for (int jobi = 0; jobi < 2; ++jobi) {
        int rb = jobi ? jp : 15 - jp;    // heavy job first
        int K = (rb + 1) * 128;
        const u16* Ph = P + (size_t)h * P_HSTR + (size_t)(rb * (rb + 1) / 2) * P_TILE;
        f32x4 acc[2][4];
        f32x4 accl[2];
#pragma unroll
        for (int mi = 0; mi < 2; ++mi) {
            accl[mi] = (f32x4){0.f, 0.f, 0.f, 0.f};
#pragma unroll
            for (int ni = 0; ni < 4; ++ni) acc[mi][ni] = (f32x4){0.f, 0.f, 0.f, 0.f};
        }
        for (int k0 = 0; k0 < K; k0 += 128) {
            const u16* At = Ph + (size_t)(k0 >> 7) * P_TILE;   // full 128-wide tile
#pragma unroll
            for (int j = 0; j < 4; ++j) {
                int d = wave * 4 + j;                          // 32 slots per buffer
                int kb = d >> 3, seg = d & 7;
                size_t roff = (size_t)(seg * 16 + lr);
                gload16(At + roff * 128 + kb * 32 + acol, As + d * 512);
                gload16(Bt + roff * T_SEQ + k0 + kb * 32 + acol, Bs + d * 512);
            }
            __syncthreads();
#pragma unroll
            for (int kb = 0; kb < 4; ++kb) {
                f16x8 af[2], bf[4];
#pragma unroll
                for (int mi = 0; mi < 2; ++mi) af[mi] = *(const f16x8*)&As[(kb * 8 + wr * 2 + mi) * 512 + l * 8];
#pragma unroll
                for (int ni = 0; ni < 4; ++ni) bf[ni] = *(const f16x8*)&Bs[(kb * 8 + wc * 4 + ni) * 512 + l * 8];
#pragma unroll
                for (int mi = 0; mi < 2; ++mi) {
#pragma unroll
                    for (int ni = 0; ni < 4; ++ni)
                        acc[mi][ni] = __builtin_amdgcn_mfma_f32_16x16x32_f16(af[mi], bf[ni], acc[mi][ni], 0, 0, 0);
                    if (nq == 0 && wc == 0)
                        accl[mi] = __builtin_amdgcn_mfma_f32_16x16x32_f16(af[mi], ones, accl[mi], 0, 0, 0);
                }
            }
            __syncthreads();
        }
        // fused contract-y epilogue (unnormalized; scale_y divides by l later)
#pragma unroll
        for (int mi = 0; mi < 2; ++mi)
#pragma unroll
            for (int rr = 0; rr < 4; ++rr) {
                int row = rb * 128 + wr * 32 + mi * 16 + quad * 4 + rr;
                uint4 qv = *(const uint4*)(q16 + (size_t)row * CDIM + h * HDIM + mb * 8);
                const u32* qw = (const u32*)&qv;
                float psum = 0.f;
#pragma unroll
                for (int ni = 0; ni < 4; ++ni) {
                    float qa = h2f((u16)(qw[ni] >> (o * 16)));   // a = 2*ni + o
                    psum = fmaf(qa, acc[mi][ni][rr], psum);
                }
                psum += __shfl_xor(psum, 8);                     // combine a parities
                if (lr < 8)
                    y16[(size_t)row * CDIM + h * HDIM + mb * 8 + lr] = f2h(psum);
            }
        if (nq == 0 && wc == 0 && lr == 0) {
#pragma unroll
            for (int mi = 0; mi < 2; ++mi) {
                int row = rb * 128 + wr * 32 + mi * 16 + quad * 4;
                *(f32x4*)(lbuf + h * T_SEQ + row) = accl[mi];
            }
        }
    }
}

// y16[i][c] *= 1/l[h=c>>6][i]  (in-place, 8 elems/thread, h constant within 8)
__global__ __launch_bounds__(256) void scale_y(const float* __restrict__ lbuf,
                                               u16* __restrict__ y16) {
    size_t idx = ((size_t)blockIdx.x * 256 + threadIdx.x) * 8;
    int i = (int)(idx >> 10);
    int c = (int)(idx & 1023);
    int h = c >> 6;
    float linv = 1.f / lbuf[h * T_SEQ + i];
    uint4 v = *(const uint4*)(y16 + idx);
    u32* w = (u32*)&v;
    uint4 outv;
    u32* ow = (u32*)&outv;
#pragma unroll
    for (int j = 0; j < 4; ++j) {
        float lo = h2f((u16)(w[j] & 0xffff)) * linv;
        float hi = h2f((u16)(w[j] >> 16)) * linv;
        ow[j] = pk(lo, hi);
    }
    *(uint4*)(y16 + idx) = outv;
}

// fp32 -> fp16 conversions: z=0 x(2M), z=1..4 Wq/Wk/Wv/Wo (1M each) into w16
__global__ __launch_bounds__(256) void cvt5(const float* __restrict__ x, const float* __restrict__ wq,
                                            const float* __restrict__ wk, const float* __restrict__ wv,
                                            const float* __restrict__ wo,
                                            u16* __restrict__ x16, u16* __restrict__ w16) {
    int z = blockIdx.y;
    size_t base = ((size_t)blockIdx.x * 256 + threadIdx.x) * 8;
    const float* src;
    u16* dst;
    size_t cnt;
    if (z == 0) { src = x; dst = x16; cnt = 2097152; }
    else if (z == 1) { src = wq; dst = w16; cnt = 1048576; }
    else if (z == 2) { src = wk; dst = w16 + 1048576; cnt = 1048576; }
    else if (z == 3) { src = wv; dst = w16 + 2097152; cnt = 1048576; }
    else { src = wo; dst = w16 + 3145728; cnt = 1048576; }
    if (base >= cnt) return;
    float4 f0 = *(const float4*)(src + base);
    float4 f1 = *(const float4*)(src + base + 4);
    uint4 o;
    o.x = pk(f0.x, f0.y); o.y = pk(f0.z, f0.w); o.z = pk(f1.x, f1.y); o.w = pk(f1.z, f1.w);
    *(uint4*)(dst + base) = o;
}

// One wave per (t,h): rotary+RMS from fp16 qkv (ld 3072); writes q16,k16 (fp16), kc (fp32).
__global__ __launch_bounds__(256) void prep_rope(const u16* __restrict__ qkv,
                                                 u16* __restrict__ q16, u16* __restrict__ k16,
                                                 float* __restrict__ kc,
                                                 const float* __restrict__ cosb, const float* __restrict__ sinb) {
    int wave = threadIdx.x >> 6, lane = threadIdx.x & 63;
    int idx = blockIdx.x * 4 + wave;
    int t = idx >> 4, h = idx & 15;
    int d = lane & 31;
    float cs = cosb[t * 32 + d];
    float sn = sinb[t * 32 + d];
    size_t b3 = (size_t)t * 3072 + h * HDIM;
    size_t b1 = (size_t)t * CDIM + h * HDIM;

    float xq = h2f(qkv[b3 + lane]);
    float oq = __shfl(xq, lane ^ 32);
    float rq = (lane < 32) ? fmaf(xq, cs, oq * sn) : fmaf(xq, cs, -oq * sn);
    float ssq = rq * rq;
#pragma unroll
    for (int m = 1; m < 64; m <<= 1) ssq += __shfl_xor(ssq, m);
    rq *= rsqrtf(ssq * (1.f / 64.f) + 1e-6f);
    q16[b1 + lane] = f2h(rq);

    float xk = h2f(qkv[b3 + 1024 + lane]);
    float ok = __shfl(xk, lane ^ 32);
    float rk = (lane < 32) ? fmaf(xk, cs, ok * sn) : fmaf(xk, cs, -ok * sn);
    float ssk = rk * rk;
#pragma unroll
    for (int m = 1; m < 64; m <<= 1) ssk += __shfl_xor(ssk, m);
    rk *= rsqrtf(ssk * (1.f / 64.f) + 1e-6f);
    k16[b1 + lane] = f2h(rk);

    float s8 = rk * rk;
    s8 += __shfl_xor(s8, 1); s8 += __shfl_xor(s8, 2); s8 += __shfl_xor(s8, 4);
    float sc2 = 1.f / fmaxf(sqrtf(s8), 1e-12f);
    float kcv = rk * sc2;
    if (lane & 7) kcv = -kcv;  // octonion conjugate
    kc[b1 + lane] = kcv;
}

// W[h][n=(m*64+a*8+e)][j] from kc (fp32, ld 1024) and v inside fp16 qkv (ld 3072, +2048)
__global__ __launch_bounds__(256) void w_pre(const float* __restrict__ kc, const u16* __restrict__ qkv,
                                             u16* __restrict__ W) {
    __shared__ float kcs[64][65];
    __shared__ float vs[64][65];
    int h = blockIdx.y;
    int j0 = blockIdx.x * 64;
    int t = threadIdx.x;
    int r = t >> 2, cq = (t & 3) * 16;
    const float* kp = kc + (size_t)(j0 + r) * CDIM + h * HDIM + cq;
    const u16* vp = qkv + (size_t)(j0 + r) * 3072 + 2048 + h * HDIM + cq;
#pragma unroll
    for (int u4 = 0; u4 < 4; ++u4) {
        float4 a = *(const float4*)(kp + u4 * 4);
        ushort4 b = *(const ushort4*)(vp + u4 * 4);
        kcs[r][cq + u4 * 4 + 0] = a.x; kcs[r][cq + u4 * 4 + 1] = a.y;
        kcs[r][cq + u4 * 4 + 2] = a.z; kcs[r][cq + u4 * 4 + 3] = a.w;
        vs[r][cq + u4 * 4 + 0] = h2f(b.x); vs[r][cq + u4 * 4 + 1] = h2f(b.y);
        vs[r][cq + u4 * 4 + 2] = h2f(b.z); vs[r][cq + u4 * 4 + 3] = h2f(b.w);
    }
    __syncthreads();
    int j = t & 63, g = t >> 6;
    u16* Wp = W + (size_t)h * W_HSTR + j0 + j;
    for (int ae = g * 16; ae < g * 16 + 16; ++ae) {
        int a = ae >> 3, e = ae & 7;
        u32 mask = 0;
#pragma unroll
        for (int qq = 0; qq < 8; ++qq) {
            int p = a ^ e ^ qq;
            u32 bit = (u32)(((SGBITS >> (a * 8 + p)) ^ (SGBITS >> ((e ^ qq) * 8 + qq))) & 1ULL);
            mask |= bit << qq;
        }
#pragma unroll
        for (int m = 0; m < 8; ++m) {
            float w = 0.f;
#pragma unroll
            for (int qq = 0; qq < 8; ++qq) {
                float t1 = kcs[j][m * 8 + (a ^ e ^ qq)] * vs[j][m * 8 + qq];
                w = ((mask >> qq) & 1) ? (w - t1) : (w + t1);
            }
            Wp[(size_t)(m * 64 + ae) * T_SEQ] = f2h(w);
        }
    }
}

extern "C" void kernel_launch(void* const* d_in, const int* in_sizes, int n_in,
                              void* d_out, int out_size, void* d_ws, size_t ws_size,
                              hipStream_t stream) {
    const float* x = (const float*)d_in[0];
    const float* cosb = (const float*)d_in[1];
    const float* sinb = (const float*)d_in[2];
    const float* Wq = (const float*)d_in[3];
    const float* Wk = (const float*)d_in[4];
    const float* Wv = (const float*)d_in[5];
    const float* Wo = (const float*)d_in[6];
    float* out = (float*)d_out;
    char* base = (char*)d_ws;
    // workspace layout (round-10 proven offsets; Z region unused)
    u16* qkv16 = (u16*)base;                      // 2048x3072 fp16   12,582,912 B
    float* kc = (float*)(base + 12582912);        // 2048x1024 fp32    8,388,608
    u16* x16 = (u16*)(base + 20971520);           //                   4,194,304
    u16* w16 = (u16*)(base + 25165824);           // 4x 1024x1024 fp16 8,388,608
    u16* q16 = (u16*)(base + 33554432);           //                   4,194,304
    u16* k16 = (u16*)(base + 37748736);           //                   4,194,304
    u16* y16 = (u16*)(base + 41943040);           //                   4,194,304
    u16* W = (u16*)(base + 46137344);             //                  33,554,432
    float* lbuf = (float*)(base + 113246208);     // 16x2048 fp32        131,072
    u16* Pbuf = (u16*)(base + 113377280);         // 16x136 tiles fp16 71,303,168 -> end 184,680,448

    cvt5<<<dim3(1024, 5), 256, 0, stream>>>(x, Wq, Wk, Wv, Wo, x16, w16);
    hgemm_f16<<<dim3(24, 32), 256, 0, stream>>>(x16, CDIM, w16, CDIM, qkv16, 3072, CDIM);
    prep_rope<<<T_SEQ * NHEAD / 4, 256, 0, stream>>>(qkv16, q16, k16, kc, cosb, sinb);
    qk_exp_p<<<16 * 136, 256, 0, stream>>>(q16, k16, Pbuf);
    w_pre<<<dim3(32, 16), 256, 0, stream>>>(kc, qkv16, W);
    pw_gemm<<<512, 512, 0, stream>>>(Pbuf, W, q16, y16, lbuf);
    scale_y<<<1024, 256, 0, stream>>>(lbuf, y16);
    hgemm_f32<<<dim3(8, 32), 256, 0, stream>>>(y16, CDIM, w16 + 3145728, CDIM, out, CDIM, CDIM);
}

// Round 16
// 277.398 us; speedup vs baseline: 1.1809x; 1.0157x over previous
//
#include <hip/hip_runtime.h>

typedef unsigned short u16;
typedef unsigned int u32;

#define T_SEQ 2048
#define NHEAD 16
#define HDIM 64
#define CDIM 1024
#define W_HSTR (512*2048)
// P: per head 136 causal tiles of 128x128 fp16, row-major tiles
#define P_HSTR 2228224   // 136*16384 elems
#define P_TILE 16384

// Octonion sign table: SG[a][n] = sign of component (a^n) of e_a * e_n.
// Byte a holds row a; bit n set => negative. (Validated end-to-end rounds 3-8.)
#define SGBITS 0xB2D8741EACC66A00ULL

// exp(s*0.125) = exp2(s*0.125/ln2); extra 2^-12 scale keeps unnormalized Z in fp16 range.
#define EXP2C 0.18033688011112042f

typedef _Float16 f16x8 __attribute__((ext_vector_type(8)));
typedef float f32x4 __attribute__((ext_vector_type(4)));

__device__ __forceinline__ float h2f(u16 u) { _Float16 h; __builtin_memcpy(&h, &u, 2); return (float)h; }
__device__ __forceinline__ u16 f2h(float f) { _Float16 h = (_Float16)f; u16 u; __builtin_memcpy(&u, &h, 2); return u; }
__device__ __forceinline__ u32 pk(float a, float b) { return (u32)f2h(a) | ((u32)f2h(b) << 16); }

// async 16B/lane global->LDS DMA; lds dest wave-uniform (HW adds lane*16)
__device__ __forceinline__ void gload16(const u16* g, u16* l) {
    __builtin_amdgcn_global_load_lds((const __attribute__((address_space(1))) u32*)g,
                                     (__attribute__((address_space(3))) u32*)l, 16, 0, 0);
}

// ---- 64x128-tile MFMA core (round-10 proven: grid utilization for skinny GEMMs) ----
// Fragment-major LDS (A seg 0..3, B seg 0..7); 4 waves as 2 wr x 2 wc; acc[2][4].
template<bool F16OUT>
__device__ __forceinline__ void hgemm64_tile(const u16* __restrict__ At, int lda,
                                             const u16* __restrict__ Bt, int ldb, int K,
                                             float* __restrict__ Cf, u16* __restrict__ Ch,
                                             int ldc, u16* As, u16* Bs) {
    int t = threadIdx.x;
    int wave = t >> 6, l = t & 63;
    int wr = wave & 1, wc = wave >> 1;
    int quad = l >> 4, lr = l & 15;
    int acol = quad * 8;
    f32x4 acc[2][4];
#pragma unroll
    for (int i = 0; i < 2; ++i)
#pragma unroll
        for (int j = 0; j < 4; ++j) acc[i][j] = (f32x4){0.f, 0.f, 0.f, 0.f};
    for (int k0 = 0; k0 < K; k0 += 64) {
#pragma unroll
        for (int j = 0; j < 2; ++j) {           // A slots: 8 total (kb 0..1 x seg 0..3)
            int dA = wave * 2 + j;
            int kb = dA >> 2, seg = dA & 3;
            gload16(At + (size_t)(seg * 16 + lr) * lda + k0 + kb * 32 + acol, As + dA * 512);
        }
#pragma unroll
        for (int j = 0; j < 4; ++j) {           // B slots: 16 total (kb 0..1 x seg 0..7)
            int dB = wave * 4 + j;
            int kb = dB >> 3, seg = dB & 7;
            gload16(Bt + (size_t)(seg * 16 + lr) * ldb + k0 + kb * 32 + acol, Bs + dB * 512);
        }
        __syncthreads();
#pragma unroll
        for (int kb = 0; kb < 2; ++kb) {
            f16x8 af[2], bf[4];
#pragma unroll
            for (int mi = 0; mi < 2; ++mi) af[mi] = *(const f16x8*)&As[(kb * 4 + wr * 2 + mi) * 512 + l * 8];
#pragma unroll
            for (int ni = 0; ni < 4; ++ni) bf[ni] = *(const f16x8*)&Bs[(kb * 8 + wc * 4 + ni) * 512 + l * 8];
#pragma unroll
            for (int mi = 0; mi < 2; ++mi)
#pragma unroll
                for (int ni = 0; ni < 4; ++ni)
                    acc[mi][ni] = __builtin_amdgcn_mfma_f32_16x16x32_f16(af[mi], bf[ni], acc[mi][ni], 0, 0, 0);
        }
        __syncthreads();
    }
#pragma unroll
    for (int mi = 0; mi < 2; ++mi)
#pragma unroll
        for (int ni = 0; ni < 4; ++ni)
#pragma unroll
            for (int rr = 0; rr < 4; ++rr) {
                int gr = wr * 32 + mi * 16 + quad * 4 + rr;
                int gc = wc * 64 + ni * 16 + lr;
                float v = acc[mi][ni][rr];
                if (F16OUT) Ch[(size_t)gr * ldc + gc] = f2h(v);
                else Cf[(size_t)gr * ldc + gc] = v;
            }
}

__global__ __launch_bounds__(256) void hgemm_f32(const u16* __restrict__ A, int lda,
                                                 const u16* __restrict__ B, int ldb,
                                                 float* __restrict__ C, int ldc, int K) {
    __shared__ u16 As[4096], Bs[8192];
    int bm = blockIdx.y * 64, bn = blockIdx.x * 128;
    hgemm64_tile<false>(A + (size_t)bm * lda, lda, B + (size_t)bn * ldb, ldb, K,
                        C + (size_t)bm * ldc + bn, nullptr, ldc, As, Bs);
}

__global__ __launch_bounds__(256) void hgemm_f16(const u16* __restrict__ A, int lda,
                                                 const u16* __restrict__ B, int ldb,
                                                 u16* __restrict__ C, int ldc, int K) {
    __shared__ u16 As[4096], Bs[8192];
    int bm = blockIdx.y * 64, bn = blockIdx.x * 128;
    hgemm64_tile<true>(A + (size_t)bm * lda, lda, B + (size_t)bn * ldb, ldb, K,
                       nullptr, C + (size_t)bm * ldc + bn, ldc, As, Bs);
}

// ---- Kernel A: one-shot P = exp(QK^T) per 128x128 causal tile ----
// 2176 blocks = 16 heads x 136 tiles (rb>=cb). QK direct from global (L2-resident),
// exp -> LDS, then coalesced row-major uint4 tile store. Pad 144 keeps 16B alignment.
__global__ __launch_bounds__(256) void qk_exp_p(const u16* __restrict__ q16,
                                                const u16* __restrict__ k16,
                                                u16* __restrict__ P) {
    __shared__ u16 Pt[128 * 144];
    int idx = blockIdx.x;
    int h = idx & 15;
    int tt = idx >> 4;                   // 0..135 triangular tile index
    int rb = 0;
    while ((rb + 1) * (rb + 2) / 2 <= tt) rb++;
    int cb = tt - rb * (rb + 1) / 2;     // 0..rb
    int t = threadIdx.x;
    int wave = t >> 6, l = t & 63;
    int wm = wave & 1, wn = wave >> 1;
    int quad = l >> 4, lr = l & 15;

    const u16* qbase = q16 + (size_t)(rb * 128 + wm * 64 + lr) * CDIM + h * HDIM + quad * 8;
    const u16* kbase = k16 + (size_t)(cb * 128 + wn * 64 + lr) * CDIM + h * HDIM + quad * 8;
    f16x8 qa[4][2], kf[4][2];
#pragma unroll
    for (int mi = 0; mi < 4; ++mi)
#pragma unroll
        for (int kb = 0; kb < 2; ++kb)
            qa[mi][kb] = *(const f16x8*)(qbase + (size_t)(mi * 16) * CDIM + kb * 32);
#pragma unroll
    for (int ni = 0; ni < 4; ++ni)
#pragma unroll
        for (int kb = 0; kb < 2; ++kb)
            kf[ni][kb] = *(const f16x8*)(kbase + (size_t)(ni * 16) * CDIM + kb * 32);

    f32x4 s[4][4];
#pragma unroll
    for (int mi = 0; mi < 4; ++mi)
#pragma unroll
        for (int ni = 0; ni < 4; ++ni) s[mi][ni] = (f32x4){0.f, 0.f, 0.f, 0.f};
#pragma unroll
    for (int kb = 0; kb < 2; ++kb)
#pragma unroll
        for (int mi = 0; mi < 4; ++mi)
#pragma unroll
            for (int ni = 0; ni < 4; ++ni)
                s[mi][ni] = __builtin_amdgcn_mfma_f32_16x16x32_f16(qa[mi][kb], kf[ni][kb], s[mi][ni], 0, 0, 0);

#pragma unroll
    for (int mi = 0; mi < 4; ++mi) {
        int row = wm * 64 + mi * 16 + quad * 4;
#pragma unroll
        for (int ni = 0; ni < 4; ++ni) {
            int col = wn * 64 + ni * 16 + lr;
#pragma unroll
            for (int rr = 0; rr < 4; ++rr) {
                bool valid = (cb < rb) | (col <= row + rr);   // same 128-block => local compare
                float p = valid ? __builtin_amdgcn_exp2f(s[mi][ni][rr] * EXP2C - 12.f) : 0.f;
                Pt[(row + rr) * 144 + col] = f2h(p);
            }
        }
    }
    __syncthreads();
    u16* Pg = P + (size_t)h * P_HSTR + (size_t)tt * P_TILE;
#pragma unroll
    for (int i = 0; i < 8; ++i) {
        int c = i * 256 + t;             // 2048 chunks of 8 elems
        int row = c >> 4, cw = c & 15;
        uint4 v = *(const uint4*)&Pt[row * 144 + cw * 8];
        *(uint4*)(Pg + row * 128 + cw * 8) = v;
    }
}

// ---- Kernel B: Z = P @ W with FUSED contract-y epilogue (round 12, best measured) ----
// Round-6 proven body (8-wave paired jobs, 17 K-units/block, 16 waves/CU).
// Epilogue: each wave's 128x64 Z-tile is one complete m-block (m = nq*2+wc;
// col = ni*16+lr -> a = 2ni+(lr>>3), e = lr&7), so y_un[i][h*64+m*8+e] =
// sum_a q16[i][h*64+m*8+a] * Z[col] is computed in-register: 4 FMAs from fp32 acc
// + shfl_xor(8) (lane-pair lr/lr+8 holds a-parities). Kills the 33.5MB Z write +
// the contract_y kernel; 1/l divide deferred to scale_y (l is cross-block).
// l = P.1 via ones-MFMA on nq==0, wc==0 waves (full causal K per job).
__global__ __launch_bounds__(512, 4) void pw_gemm(const u16* __restrict__ P,
                                                  const u16* __restrict__ W,
                                                  const u16* __restrict__ q16,
                                                  u16* __restrict__ y16,
                                                  float* __restrict__ lbuf) {
    __shared__ u16 As[8192], Bs[8192];
    int b = blockIdx.x;
    int jp = b >> 6;                     // 0..7 rb-pair index
    int i6 = b & 63;
    int h = ((i6 & 7) << 1) | ((i6 >> 3) & 1);
    int nq = i6 >> 4;
    const u16* Bt = W + (size_t)h * W_HSTR + (size_t)(nq * 128) * T_SEQ;
    int t = threadIdx.x;
    int wave = t >> 6, l = t & 63;
    int wr = wave >> 1, wc = wave & 1;   // wave tile: rows wr*32, cols wc*64
    int quad = l >> 4, lr = l & 15;
    int acol = quad * 8;
    int mb = nq * 2 + wc;                // this wave's m-block (0..7)
    int o = lr >> 3;                     // a parity held by this lane
    f16x8 ones;
#pragma unroll
    for (int j = 0; j < 8; ++j) ones[j] = (_Float16)1.0f;

#pragma unroll 1
    for (int jobi = 0; jobi < 2; ++jobi) {
        int rb = jobi ? jp : 15 - jp;    // heavy job first
        int K = (rb + 1) * 128;
        const u16* Ph = P + (size_t)h * P_HSTR + (size_t)(rb * (rb + 1) / 2) * P_TILE;
        f32x4 acc[2][4];
        f32x4 accl[2];
#pragma unroll
        for (int mi = 0; mi < 2; ++mi) {
            accl[mi] = (f32x4){0.f, 0.f, 0.f, 0.f};
#pragma unroll
            for (int ni = 0; ni < 4; ++ni) acc[mi][ni] = (f32x4){0.f, 0.f, 0.f, 0.f};
        }
        for (int k0 = 0; k0 < K; k0 += 64) {
            const u16* At = Ph + (size_t)(k0 >> 7) * P_TILE + (k0 & 64);  // tile base + k-half
#pragma unroll
            for (int j = 0; j < 2; ++j) {
                int d = wave * 2 + j;
                int kb = d >> 3, seg = d & 7;
                size_t roff = (size_t)(seg * 16 + lr);
                gload16(At + roff * 128 + kb * 32 + acol, As + d * 512);
                gload16(Bt + roff * T_SEQ + k0 + kb * 32 + acol, Bs + d * 512);
            }
            __syncthreads();
#pragma unroll
            for (int kb = 0; kb < 2; ++kb) {
                f16x8 af[2], bf[4];
#pragma unroll
                for (int mi = 0; mi < 2; ++mi) af[mi] = *(const f16x8*)&As[(kb * 8 + wr * 2 + mi) * 512 + l * 8];
#pragma unroll
                for (int ni = 0; ni < 4; ++ni) bf[ni] = *(const f16x8*)&Bs[(kb * 8 + wc * 4 + ni) * 512 + l * 8];
#pragma unroll
                for (int mi = 0; mi < 2; ++mi) {
#pragma unroll
                    for (int ni = 0; ni < 4; ++ni)
                        acc[mi][ni] = __builtin_amdgcn_mfma_f32_16x16x32_f16(af[mi], bf[ni], acc[mi][ni], 0, 0, 0);
                    if (nq == 0 && wc == 0)
                        accl[mi] = __builtin_amdgcn_mfma_f32_16x16x32_f16(af[mi], ones, accl[mi], 0, 0, 0);
                }
            }
            __syncthreads();
        }
        // fused contract-y epilogue (unnormalized; scale_y divides by l later)
#pragma unroll
        for (int mi = 0; mi < 2; ++mi)
#pragma unroll
            for (int rr = 0; rr < 4; ++rr) {
                int row = rb * 128 + wr * 32 + mi * 16 + quad * 4 + rr;
                uint4 qv = *(const uint4*)(q16 + (size_t)row * CDIM + h * HDIM + mb * 8);
                const u32* qw = (const u32*)&qv;
                float psum = 0.f;
#pragma unroll
                for (int ni = 0; ni < 4; ++ni) {
                    float qa = h2f((u16)(qw[ni] >> (o * 16)));   // a = 2*ni + o
                    psum = fmaf(qa, acc[mi][ni][rr], psum);
                }
                psum += __shfl_xor(psum, 8);                     // combine a parities
                if (lr < 8)
                    y16[(size_t)row * CDIM + h * HDIM + mb * 8 + lr] = f2h(psum);
            }
        if (nq == 0 && wc == 0 && lr == 0) {
#pragma unroll
            for (int mi = 0; mi < 2; ++mi) {
                int row = rb * 128 + wr * 32 + mi * 16 + quad * 4;
                *(f32x4*)(lbuf + h * T_SEQ + row) = accl[mi];
            }
        }
    }
}

// y16[i][c] *= 1/l[h=c>>6][i]  (in-place, 8 elems/thread, h constant within 8)
__global__ __launch_bounds__(256) void scale_y(const float* __restrict__ lbuf,
                                               u16* __restrict__ y16) {
    size_t idx = ((size_t)blockIdx.x * 256 + threadIdx.x) * 8;
    int i = (int)(idx >> 10);
    int c = (int)(idx & 1023);
    int h = c >> 6;
    float linv = 1.f / lbuf[h * T_SEQ + i];
    uint4 v = *(const uint4*)(y16 + idx);
    u32* w = (u32*)&v;
    uint4 outv;
    u32* ow = (u32*)&outv;
#pragma unroll
    for (int j = 0; j < 4; ++j) {
        float lo = h2f((u16)(w[j] & 0xffff)) * linv;
        float hi = h2f((u16)(w[j] >> 16)) * linv;
        ow[j] = pk(lo, hi);
    }
    *(uint4*)(y16 + idx) = outv;
}

// fp32 -> fp16 conversions: z=0 x(2M), z=1..4 Wq/Wk/Wv/Wo (1M each) into w16
__global__ __launch_bounds__(256) void cvt5(const float* __restrict__ x, const float* __restrict__ wq,
                                            const float* __restrict__ wk, const float* __restrict__ wv,
                                            const float* __restrict__ wo,
                                            u16* __restrict__ x16, u16* __restrict__ w16) {
    int z = blockIdx.y;
    size_t base = ((size_t)blockIdx.x * 256 + threadIdx.x) * 8;
    const float* src;
    u16* dst;
    size_t cnt;
    if (z == 0) { src = x; dst = x16; cnt = 2097152; }
    else if (z == 1) { src = wq; dst = w16; cnt = 1048576; }
    else if (z == 2) { src = wk; dst = w16 + 1048576; cnt = 1048576; }
    else if (z == 3) { src = wv; dst = w16 + 2097152; cnt = 1048576; }
    else { src = wo; dst = w16 + 3145728; cnt = 1048576; }
    if (base >= cnt) return;
    float4 f0 = *(const float4*)(src + base);
    float4 f1 = *(const float4*)(src + base + 4);
    uint4 o;
    o.x = pk(f0.x, f0.y); o.y = pk(f0.z, f0.w); o.z = pk(f1.x, f1.y); o.w = pk(f1.z, f1.w);
    *(uint4*)(dst + base) = o;
}

// One wave per (t,h): rotary+RMS from fp16 qkv (ld 3072); writes q16,k16 (fp16), kc (fp32).
__global__ __launch_bounds__(256) void prep_rope(const u16* __restrict__ qkv,
                                                 u16* __restrict__ q16, u16* __restrict__ k16,
                                                 float* __restrict__ kc,
                                                 const float* __restrict__ cosb, const float* __restrict__ sinb) {
    int wave = threadIdx.x >> 6, lane = threadIdx.x & 63;
    int idx = blockIdx.x * 4 + wave;
    int t = idx >> 4, h = idx & 15;
    int d = lane & 31;
    float cs = cosb[t * 32 + d];
    float sn = sinb[t * 32 + d];
    size_t b3 = (size_t)t * 3072 + h * HDIM;
    size_t b1 = (size_t)t * CDIM + h * HDIM;

    float xq = h2f(qkv[b3 + lane]);
    float oq = __shfl(xq, lane ^ 32);
    float rq = (lane < 32) ? fmaf(xq, cs, oq * sn) : fmaf(xq, cs, -oq * sn);
    float ssq = rq * rq;
#pragma unroll
    for (int m = 1; m < 64; m <<= 1) ssq += __shfl_xor(ssq, m);
    rq *= rsqrtf(ssq * (1.f / 64.f) + 1e-6f);
    q16[b1 + lane] = f2h(rq);

    float xk = h2f(qkv[b3 + 1024 + lane]);
    float ok = __shfl(xk, lane ^ 32);
    float rk = (lane < 32) ? fmaf(xk, cs, ok * sn) : fmaf(xk, cs, -ok * sn);
    float ssk = rk * rk;
#pragma unroll
    for (int m = 1; m < 64; m <<= 1) ssk += __shfl_xor(ssk, m);
    rk *= rsqrtf(ssk * (1.f / 64.f) + 1e-6f);
    k16[b1 + lane] = f2h(rk);

    float s8 = rk * rk;
    s8 += __shfl_xor(s8, 1); s8 += __shfl_xor(s8, 2); s8 += __shfl_xor(s8, 4);
    float sc2 = 1.f / fmaxf(sqrtf(s8), 1e-12f);
    float kcv = rk * sc2;
    if (lane & 7) kcv = -kcv;  // octonion conjugate
    kc[b1 + lane] = kcv;
}

// W[h][n=(m*64+a*8+e)][j] from kc (fp32, ld 1024) and v inside fp16 qkv (ld 3072, +2048)
__global__ __launch_bounds__(256) void w_pre(const float* __restrict__ kc, const u16* __restrict__ qkv,
                                             u16* __restrict__ W) {
    __shared__ float kcs[64][65];
    __shared__ float vs[64][65];
    int h = blockIdx.y;
    int j0 = blockIdx.x * 64;
    int t = threadIdx.x;
    int r = t >> 2, cq = (t & 3) * 16;
    const float* kp = kc + (size_t)(j0 + r) * CDIM + h * HDIM + cq;
    const u16* vp = qkv + (size_t)(j0 + r) * 3072 + 2048 + h * HDIM + cq;
#pragma unroll
    for (int u4 = 0; u4 < 4; ++u4) {
        float4 a = *(const float4*)(kp + u4 * 4);
        ushort4 b = *(const ushort4*)(vp + u4 * 4);
        kcs[r][cq + u4 * 4 + 0] = a.x; kcs[r][cq + u4 * 4 + 1] = a.y;
        kcs[r][cq + u4 * 4 + 2] = a.z; kcs[r][cq + u4 * 4 + 3] = a.w;
        vs[r][cq + u4 * 4 + 0] = h2f(b.x); vs[r][cq + u4 * 4 + 1] = h2f(b.y);
        vs[r][cq + u4 * 4 + 2] = h2f(b.z); vs[r][cq + u4 * 4 + 3] = h2f(b.w);
    }
    __syncthreads();
    int j = t & 63, g = t >> 6;
    u16* Wp = W + (size_t)h * W_HSTR + j0 + j;
    for (int ae = g * 16; ae < g * 16 + 16; ++ae) {
        int a = ae >> 3, e = ae & 7;
        u32 mask = 0;
#pragma unroll
        for (int qq = 0; qq < 8; ++qq) {
            int p = a ^ e ^ qq;
            u32 bit = (u32)(((SGBITS >> (a * 8 + p)) ^ (SGBITS >> ((e ^ qq) * 8 + qq))) & 1ULL);
            mask |= bit << qq;
        }
#pragma unroll
        for (int m = 0; m < 8; ++m) {
            float w = 0.f;
#pragma unroll
            for (int qq = 0; qq < 8; ++qq) {
                float t1 = kcs[j][m * 8 + (a ^ e ^ qq)] * vs[j][m * 8 + qq];
                w = ((mask >> qq) & 1) ? (w - t1) : (w + t1);
            }
            Wp[(size_t)(m * 64 + ae) * T_SEQ] = f2h(w);
        }
    }
}

extern "C" void kernel_launch(void* const* d_in, const int* in_sizes, int n_in,
                              void* d_out, int out_size, void* d_ws, size_t ws_size,
                              hipStream_t stream) {
    const float* x = (const float*)d_in[0];
    const float* cosb = (const float*)d_in[1];
    const float* sinb = (const float*)d_in[2];
    const float* Wq = (const float*)d_in[3];
    const float* Wk = (const float*)d_in[4];
    const float* Wv = (const float*)d_in[5];
    const float* Wo = (const float*)d_in[6];
    float* out = (float*)d_out;
    char* base = (char*)d_ws;
    // workspace layout (round-10 proven offsets; Z region unused)
    u16* qkv16 = (u16*)base;                      // 2048x3072 fp16   12,582,912 B
    float* kc = (float*)(base + 12582912);        // 2048x1024 fp32    8,388,608
    u16* x16 = (u16*)(base + 20971520);           //                   4,194,304
    u16* w16 = (u16*)(base + 25165824);           // 4x 1024x1024 fp16 8,388,608
    u16* q16 = (u16*)(base + 33554432);           //                   4,194,304
    u16* k16 = (u16*)(base + 37748736);           //                   4,194,304
    u16* y16 = (u16*)(base + 41943040);           //                   4,194,304
    u16* W = (u16*)(base + 46137344);             //                  33,554,432
    float* lbuf = (float*)(base + 113246208);     // 16x2048 fp32        131,072
    u16* Pbuf = (u16*)(base + 113377280);         // 16x136 tiles fp16 71,303,168 -> end 184,680,448

    cvt5<<<dim3(1024, 5), 256, 0, stream>>>(x, Wq, Wk, Wv, Wo, x16, w16);
    hgemm_f16<<<dim3(24, 32), 256, 0, stream>>>(x16, CDIM, w16, CDIM, qkv16, 3072, CDIM);
    prep_rope<<<T_SEQ * NHEAD / 4, 256, 0, stream>>>(qkv16, q16, k16, kc, cosb, sinb);
    qk_exp_p<<<16 * 136, 256, 0, stream>>>(q16, k16, Pbuf);
    w_pre<<<dim3(32, 16), 256, 0, stream>>>(kc, qkv16, W);
    pw_gemm<<<512, 512, 0, stream>>>(Pbuf, W, q16, y16, lbuf);
    scale_y<<<1024, 256, 0, stream>>>(lbuf, y16);
    hgemm_f32<<<dim3(8, 32), 256, 0, stream>>>(y16, CDIM, w16 + 3145728, CDIM, out, CDIM, CDIM);
}